// Round 6
// baseline (479.505 us; speedup 1.0000x reference)
//
#include <hip/hip_runtime.h>
#include <hip/hip_bf16.h>

// Problem constants (fixed by reference)
constexpr int NN   = 50000;   // nodes
constexpr int NE   = 800000;  // edges per relation
constexpr int NR   = 3;       // relations
constexpr int DIN  = 96;
constexpr int DH   = 96;
constexpr int DOUT = 64;
constexpr int SLOT = 64;      // max in-degree slots (Poisson(16): P(>64) ~ 1e-22)

// Binning parameters
constexpr int NBUCK = 196;    // ceil(NN/256): bucket = dst >> 8
constexpr int BCAP  = 4608;   // global per-bucket capacity (mean 4096, +8 sigma)
constexpr int LCAP  = 48;     // phase-1 LDS per-bucket capacity (mean 16/chunk)
constexpr int P1B   = 256;    // phase-1 blocks per relation
constexpr int CHUNK = NE / P1B;  // 3125 edges per block

typedef __attribute__((ext_vector_type(8))) short bf16x8;  // MFMA A/B frag (4 VGPRs)
typedef __attribute__((ext_vector_type(4))) float f32x4;   // MFMA C/D frag

// ---- bf16 helpers (RNE) ----------------------------------------------------
__device__ __forceinline__ unsigned short f2b(float f) {
    unsigned int u = __float_as_uint(f);
    u += 0x7fffu + ((u >> 16) & 1u);       // round-to-nearest-even
    return (unsigned short)(u >> 16);
}
__device__ __forceinline__ float blo(unsigned int u) { return __uint_as_float(u << 16); }
__device__ __forceinline__ float bhi(unsigned int u) { return __uint_as_float(u & 0xffff0000u); }
__device__ __forceinline__ unsigned int pack2(float lo, float hi) {
    return (unsigned int)f2b(lo) | ((unsigned int)f2b(hi) << 16);
}

struct __align__(4) U3 { unsigned int x, y, z; };          // 12B row-slice gather

// ---------------------------------------------------------------------------
// Binning phase 1: scatter edges into coarse (relation, dst>>8) buckets.
// LDS-staged: per-edge LDS atomic append, then ONE global atomic + coalesced
// run per bucket per block. Overflow falls back to direct global append.
// ---------------------------------------------------------------------------
__global__ __launch_bounds__(512)
void bucket_scatter_kernel(const int* __restrict__ src,
                           const int* __restrict__ dst,
                           int* __restrict__ bcount,          // [NR*NBUCK]
                           unsigned int* __restrict__ gbuck)  // [NR*NBUCK][BCAP]
{
    __shared__ unsigned int lbuf[NBUCK][LCAP];   // 37.6 KB
    __shared__ int lcnt[NBUCK];

    const int blk = blockIdx.x;                  // 0 .. NR*P1B-1
    const int r   = blk / P1B;
    const int e0  = (blk % P1B) * CHUNK;
    const int tid = threadIdx.x;

    for (int i = tid; i < NBUCK; i += 512) lcnt[i] = 0;
    __syncthreads();

    const int* sr = src + (size_t)r * NE;
    const int* dr = dst + (size_t)r * NE;
    for (int i = e0 + tid; i < e0 + CHUNK; i += 512) {
        int d = dr[i];
        int s = sr[i];
        int b = d >> 8;
        unsigned int entry = ((unsigned int)(d & 255) << 16) | (unsigned int)s;
        int pos = atomicAdd(&lcnt[b], 1);
        if (pos < LCAP) {
            lbuf[b][pos] = entry;
        } else {                                  // ~1e-6 probability path
            int g = atomicAdd(&bcount[r * NBUCK + b], 1);
            if (g < BCAP) gbuck[(size_t)(r * NBUCK + b) * BCAP + g] = entry;
        }
    }
    __syncthreads();

    // flush: wave w handles buckets w, w+8, ... (8 waves of 64)
    const int w = tid >> 6, l = tid & 63;
    for (int b = w; b < NBUCK; b += 8) {
        int cnt = lcnt[b];
        if (cnt > LCAP) cnt = LCAP;
        if (cnt == 0) continue;
        int base = 0;
        if (l == 0) base = atomicAdd(&bcount[r * NBUCK + b], cnt);
        base = __shfl(base, 0);
        if (l < cnt) {
            int g = base + l;
            if (g < BCAP) gbuck[(size_t)(r * NBUCK + b) * BCAP + g] = lbuf[b][l];
        }
    }
}

// ---------------------------------------------------------------------------
// Binning phase 2: one block per (relation,bucket). Build the 256-node slot
// lists in LDS (LDS atomics), then write slots + true deg fully coalesced.
// ---------------------------------------------------------------------------
__global__ __launch_bounds__(512)
void bucket_build_kernel(const unsigned int* __restrict__ gbuck,
                         const int* __restrict__ bcount,
                         unsigned short* __restrict__ slots,   // [NR*NN][SLOT]
                         int* __restrict__ deg)                // [NR*NN]
{
    __shared__ unsigned short lslot[256][SLOT];   // 32 KB
    __shared__ int lcnt[256];

    const int rb = blockIdx.x;                    // 0 .. NR*NBUCK-1
    const int r  = rb / NBUCK, b = rb % NBUCK;
    const int nbase = b * 256;
    int nb = NN - nbase; if (nb > 256) nb = 256;
    const int tid = threadIdx.x;

    for (int i = tid; i < 256; i += 512) lcnt[i] = 0;
    __syncthreads();

    int m = bcount[rb];
    if (m > BCAP) m = BCAP;
    const unsigned int* eb = gbuck + (size_t)rb * BCAP;
    for (int i = tid; i < m; i += 512) {
        unsigned int e = eb[i];
        int nl = e >> 16;                          // dst & 255
        int pos = atomicAdd(&lcnt[nl], 1);
        if (pos < SLOT) lslot[nl][pos] = (unsigned short)(e & 0xffffu);
    }
    __syncthreads();

    for (int j = tid; j < nb; j += 512) deg[r * NN + nbase + j] = lcnt[j];

    const unsigned int* ls32 = reinterpret_cast<const unsigned int*>(&lslot[0][0]);
    unsigned int* gs32 = reinterpret_cast<unsigned int*>(
        slots + ((size_t)r * NN + nbase) * SLOT);
    const int tot = nb * (SLOT / 2);
    for (int i = tid; i < tot; i += 512) gs32[i] = ls32[i];
}

// ---- f32 -> bf16 bulk convert (8 elems/thread) -----------------------------
__global__ void f32_to_bf16_kernel(const float* __restrict__ in,
                                   unsigned short* __restrict__ out, int n)
{
    int i = (blockIdx.x * 256 + threadIdx.x) * 8;
    if (i >= n) return;
    float4 a = *reinterpret_cast<const float4*>(in + i);
    float4 b = *reinterpret_cast<const float4*>(in + i + 4);
    uint4 o;
    o.x = pack2(a.x, a.y);
    o.y = pack2(a.z, a.w);
    o.z = pack2(b.x, b.y);
    o.w = pack2(b.z, b.w);
    *reinterpret_cast<uint4*>(out + i) = o;
}

// ---- weight transpose: W[r][k][n] f32 -> WT[r][n][k] bf16 ------------------
__global__ void wT_kernel(const float* __restrict__ in,
                          unsigned short* __restrict__ out,
                          int KD, int ND, int tot)
{
    int gid = blockIdx.x * 256 + threadIdx.x;
    if (gid >= tot) return;
    int k = gid % KD;
    int rn = gid / KD;
    int n = rn % ND;
    int r = rn / ND;
    out[gid] = f2b(in[((size_t)r * KD + k) * ND + n]);
}

// ---------------------------------------------------------------------------
// Mean-aggregation, all 3 relations, full 96 dims. 16 lanes per (rel,node);
// lane t gathers 12B (dwords 3t..3t+2) of each 192B source row (dwordx3).
// Slot indices fetched 8-at-a-time as uint4 (broadcast across the 16 lanes).
// ---------------------------------------------------------------------------
__global__ __launch_bounds__(256)
void agg_kernel(const unsigned int* __restrict__ Hb,        // [NN][48] dwords
                const unsigned short* __restrict__ slots,   // [NR*NN][SLOT]
                const int* __restrict__ deg,                // [NR*NN]
                unsigned int* __restrict__ aggb)            // [NR][NN][48]
{
    int gid = blockIdx.x * 256 + threadIdx.x;
    int grp = gid >> 4, t = gid & 15;
    if (grp >= NR * NN) return;
    const unsigned short* sl = slots + (size_t)grp * SLOT;
    int e = deg[grp];
    if (e > SLOT) e = SLOT;

    float a0 = 0.f, a1 = 0.f, a2 = 0.f, a3 = 0.f, a4 = 0.f, a5 = 0.f;
    int i = 0;
    for (; i + 8 <= e; i += 8) {
        uint4 iv = *reinterpret_cast<const uint4*>(sl + i);   // 8 u16 indices
        unsigned int idx[8] = { iv.x & 0xffffu, iv.x >> 16,
                                iv.y & 0xffffu, iv.y >> 16,
                                iv.z & 0xffffu, iv.z >> 16,
                                iv.w & 0xffffu, iv.w >> 16 };
        U3 v[8];
        #pragma unroll
        for (int q = 0; q < 8; ++q)
            v[q] = *reinterpret_cast<const U3*>(Hb + (size_t)idx[q] * 48 + 3 * t);
        #pragma unroll
        for (int q = 0; q < 8; ++q) {
            a0 += blo(v[q].x); a1 += bhi(v[q].x);
            a2 += blo(v[q].y); a3 += bhi(v[q].y);
            a4 += blo(v[q].z); a5 += bhi(v[q].z);
        }
    }
    for (; i < e; ++i) {
        unsigned int idx = sl[i];
        U3 v = *reinterpret_cast<const U3*>(Hb + (size_t)idx * 48 + 3 * t);
        a0 += blo(v.x); a1 += bhi(v.x);
        a2 += blo(v.y); a3 += bhi(v.y);
        a4 += blo(v.z); a5 += bhi(v.z);
    }
    float inv = 1.0f / (float)(e > 0 ? e : 1);
    unsigned int* o = aggb + (size_t)grp * 48 + 3 * t;   // grp = r*NN+n
    o[0] = pack2(a0 * inv, a1 * inv);
    o[1] = pack2(a2 * inv, a3 * inv);
    o[2] = pack2(a4 * inv, a5 * inv);
}

// ---------------------------------------------------------------------------
// MFMA layer: 4 waves/block, each wave owns 16 nodes and computes all NOUT
// cols for all 3 relations:  res = mean_r tanh(X@Ws_r + AGG_r@Wn_r + b_r).
// A-frags: lane l holds row (l&15), k = (l>>4)*8..+7 -> 16B contiguous loads
// from row-major bf16. B-frags from pre-transposed WT[n][k] (L2-hot).
// D-layout (m89-verified): col = lane&15, row = (lane>>4)*4 + j.
// Layer 1 writes o16 IN PLACE over Hb (each row is read only by its owner
// wave's A-frag loads, which precede its stores; clamped tail reads are
// discarded) -- saves a 9.6MB buffer.
// ---------------------------------------------------------------------------
template <int NOUT, bool OUT16>
__global__ __launch_bounds__(256)
void mfma_layer_kernel(const unsigned short* Hb,                // [NN][96] (may alias o16)
                       const unsigned short* __restrict__ aggb, // [NR][NN][96]
                       const unsigned short* __restrict__ Wts,  // [NR][NOUT][96] bf16 (Ws^T)
                       const unsigned short* __restrict__ Wtn,  // [NR][NOUT][96]
                       const float* __restrict__ bias,          // [NR][NOUT]
                       unsigned short* o16,                     // [NN][96] bf16
                       float* __restrict__ o32)                 // [NN][NOUT] f32
{
    const int w    = threadIdx.x >> 6;           // wave 0..3
    const int l    = threadIdx.x & 63;
    const int n0   = blockIdx.x * 64 + w * 16;   // wave's first node
    const int arow = l & 15, asel = l >> 4;
    int na = n0 + arow;
    if (na > NN - 1) na = NN - 1;                // clamp (stores guarded)

    bf16x8 ax[3], ag[NR][3];
    {
        const unsigned short* xr = Hb + (size_t)na * 96 + asel * 8;
        #pragma unroll
        for (int kb = 0; kb < 3; ++kb)
            ax[kb] = *reinterpret_cast<const bf16x8*>(xr + kb * 32);
        #pragma unroll
        for (int r = 0; r < NR; ++r) {
            const unsigned short* gr = aggb + ((size_t)r * NN + na) * 96 + asel * 8;
            #pragma unroll
            for (int kb = 0; kb < 3; ++kb)
                ag[r][kb] = *reinterpret_cast<const bf16x8*>(gr + kb * 32);
        }
    }

    constexpr int NC = NOUT / 16;
    #pragma unroll
    for (int c = 0; c < NC; ++c) {
        f32x4 acc[NR];
        #pragma unroll
        for (int r = 0; r < NR; ++r) acc[r] = (f32x4){0.f, 0.f, 0.f, 0.f};

        #pragma unroll
        for (int r = 0; r < NR; ++r) {
            const unsigned short* bs = Wts + ((size_t)r * NOUT + c * 16 + arow) * 96 + asel * 8;
            const unsigned short* bn = Wtn + ((size_t)r * NOUT + c * 16 + arow) * 96 + asel * 8;
            #pragma unroll
            for (int kb = 0; kb < 3; ++kb) {
                acc[r] = __builtin_amdgcn_mfma_f32_16x16x32_bf16(
                    ax[kb], *reinterpret_cast<const bf16x8*>(bs + kb * 32), acc[r], 0, 0, 0);
                acc[r] = __builtin_amdgcn_mfma_f32_16x16x32_bf16(
                    ag[r][kb], *reinterpret_cast<const bf16x8*>(bn + kb * 32), acc[r], 0, 0, 0);
            }
        }

        const int col = c * 16 + arow;
        const float b0 = bias[col];
        const float b1 = bias[NOUT + col];
        const float b2 = bias[2 * NOUT + col];
        #pragma unroll
        for (int j = 0; j < 4; ++j) {
            int node = n0 + asel * 4 + j;
            if (node < NN) {
                float v = (tanhf(acc[0][j] + b0) + tanhf(acc[1][j] + b1)
                         + tanhf(acc[2][j] + b2)) * (1.0f / 3.0f);
                if (OUT16) o16[(size_t)node * 96 + col] = f2b(v);
                else       o32[(size_t)node * DOUT + col] = v;
            }
        }
    }
}

// ---------------------------------------------------------------------------
extern "C" void kernel_launch(void* const* d_in, const int* in_sizes, int n_in,
                              void* d_out, int out_size, void* d_ws, size_t ws_size,
                              hipStream_t stream)
{
    const float* x   = (const float*)d_in[0];
    const int*   src = (const int*)d_in[1];
    const int*   dst = (const int*)d_in[2];
    const float* Ws1 = (const float*)d_in[3];
    const float* Wn1 = (const float*)d_in[4];
    const float* b1  = (const float*)d_in[5];
    const float* Ws2 = (const float*)d_in[6];
    const float* Wn2 = (const float*)d_in[7];
    const float* b2  = (const float*)d_in[8];
    float* out = (float*)d_out;

    // Workspace layout (256B-aligned), ~58.4 MB total (same as round 5).
    char* ws = (char*)d_ws;
    size_t o = 0;
    auto alloc = [&](size_t bytes) {
        size_t p = o;
        o += (bytes + 255) & ~(size_t)255;
        return p;
    };
    int* deg = (int*)(ws + alloc((size_t)NR * NN * 4));                          // 0.6 MB
    unsigned short* slots = (unsigned short*)(ws + alloc((size_t)NR * NN * SLOT * 2)); // 19.2 MB
    unsigned short* xb = (unsigned short*)(ws + alloc((size_t)NN * 96 * 2));     // 9.6 MB (x, then h1 in place)
    unsigned short* aggb = (unsigned short*)(ws + alloc((size_t)NR * NN * 96 * 2)); // 28.8 MB
    unsigned short* wt = (unsigned short*)(ws + alloc((size_t)(2 * NR * DIN * DH
                                                    + 2 * NR * DH * DOUT) * 2)); // 0.18 MB
    int* bcount = (int*)(ws + alloc((size_t)NR * NBUCK * 4));                    // 2.3 KB
    unsigned short* wt1s = wt;                         // [3][96][96]
    unsigned short* wt1n = wt1s + NR * DIN * DH;       // [3][96][96]
    unsigned short* wt2s = wt1n + NR * DIN * DH;       // [3][64][96]
    unsigned short* wt2n = wt2s + NR * DH * DOUT;      // [3][64][96]
    // Coarse-bucket buffer (10.8 MB) aliases aggb: binning completes before
    // the first agg_kernel writes aggb (same stream, sequential).
    unsigned int* gbuck = (unsigned int*)aggb;

    // --- binning (two-phase, LDS-staged; replaces per-edge global atomics) ---
    hipMemsetAsync(bcount, 0, (size_t)NR * NBUCK * 4, stream);
    bucket_scatter_kernel<<<NR * P1B, 512, 0, stream>>>(src, dst, bcount, gbuck);
    bucket_build_kernel<<<NR * NBUCK, 512, 0, stream>>>(gbuck, bcount, slots, deg);

    // --- dtype/layout prep ---
    f32_to_bf16_kernel<<<(NN * 96 / 8 + 255) / 256, 256, 0, stream>>>(x, xb, NN * 96);
    wT_kernel<<<(NR * DIN * DH + 255) / 256, 256, 0, stream>>>(Ws1, wt1s, DIN, DH, NR * DIN * DH);
    wT_kernel<<<(NR * DIN * DH + 255) / 256, 256, 0, stream>>>(Wn1, wt1n, DIN, DH, NR * DIN * DH);
    wT_kernel<<<(NR * DH * DOUT + 255) / 256, 256, 0, stream>>>(Ws2, wt2s, DH, DOUT, NR * DH * DOUT);
    wT_kernel<<<(NR * DH * DOUT + 255) / 256, 256, 0, stream>>>(Wn2, wt2n, DH, DOUT, NR * DH * DOUT);

    constexpr int AGG_GRID  = NR * NN * 16 / 256;      // 9375
    constexpr int GEMM_GRID = (NN + 63) / 64;          // 782

    // --- Layer 1: h1 (bf16, in place over xb) ---
    agg_kernel<<<AGG_GRID, 256, 0, stream>>>(
        (const unsigned int*)xb, slots, deg, (unsigned int*)aggb);
    mfma_layer_kernel<DH, true><<<GEMM_GRID, 256, 0, stream>>>(
        xb, aggb, wt1s, wt1n, b1, xb, (float*)nullptr);

    // --- Layer 2: out (f32) ---
    agg_kernel<<<AGG_GRID, 256, 0, stream>>>(
        (const unsigned int*)xb, slots, deg, (unsigned int*)aggb);
    mfma_layer_kernel<DOUT, false><<<GEMM_GRID, 256, 0, stream>>>(
        xb, aggb, wt2s, wt2n, b2, (unsigned short*)nullptr, out);
}

// Round 7
// 233.953 us; speedup vs baseline: 2.0496x; 2.0496x over previous
//
#include <hip/hip_runtime.h>
#include <hip/hip_bf16.h>

// Problem constants (fixed by reference)
constexpr int NN   = 50000;   // nodes
constexpr int NE   = 800000;  // edges per relation
constexpr int NR   = 3;       // relations
constexpr int DIN  = 96;
constexpr int DH   = 96;
constexpr int DOUT = 64;
constexpr int SLOT = 64;      // max in-degree slots (Poisson(16): P(>64) ~ 1e-22)

// Binning parameters (zero global atomics; block-private runs + scan offsets)
constexpr int NBUCK   = 196;       // bucket = dst >> 8 (256 nodes per bucket)
constexpr int LCAP    = 56;        // per-(block,bucket) cap; Poisson(16) P(>56)~1e-11
constexpr int P1B     = 256;       // phase-A blocks per relation
constexpr int CHUNK   = NE / P1B;  // 3125 edges per block (exact)
constexpr int BSTRIDE = 3200;      // gbuck ints per block (>= CHUNK, padded)
constexpr int LSTRIDE = 200;       // lofs ints per block (197 used)

typedef __attribute__((ext_vector_type(8))) short bf16x8;  // MFMA A/B frag (4 VGPRs)
typedef __attribute__((ext_vector_type(4))) float f32x4;   // MFMA C/D frag

// ---- bf16 helpers (RNE) ----------------------------------------------------
__device__ __forceinline__ unsigned short f2b(float f) {
    unsigned int u = __float_as_uint(f);
    u += 0x7fffu + ((u >> 16) & 1u);       // round-to-nearest-even
    return (unsigned short)(u >> 16);
}
__device__ __forceinline__ float blo(unsigned int u) { return __uint_as_float(u << 16); }
__device__ __forceinline__ float bhi(unsigned int u) { return __uint_as_float(u & 0xffff0000u); }
__device__ __forceinline__ unsigned int pack2(float lo, float hi) {
    return (unsigned int)f2b(lo) | ((unsigned int)f2b(hi) << 16);
}

struct __align__(4) U3 { unsigned int x, y, z; };          // 12B row-slice gather

// ---------------------------------------------------------------------------
// Binning phase A: per-block LDS binning -> in-LDS scan -> block-private
// contiguous flush. NO global atomics anywhere; all global writes coalesced.
// ---------------------------------------------------------------------------
__global__ __launch_bounds__(512)
void bin_scatter_kernel(const int* __restrict__ src,
                        const int* __restrict__ dst,
                        unsigned int* __restrict__ gbuck,   // [NR*P1B][BSTRIDE]
                        int* __restrict__ glofs)            // [NR*P1B][LSTRIDE]
{
    __shared__ unsigned int lbuf[NBUCK][LCAP];   // 43.9 KB
    __shared__ int lcnt[NBUCK];
    __shared__ int sa[256], sb[256];             // scan ping-pong
    __shared__ int lofs[NBUCK + 1];

    const int blk = blockIdx.x;                  // 0 .. NR*P1B-1
    const int r   = blk >> 8;                    // / P1B
    const int c   = blk & 255;                   // % P1B
    const int tid = threadIdx.x;

    for (int i = tid; i < NBUCK; i += 512) lcnt[i] = 0;
    __syncthreads();

    // per-edge LDS binning (coalesced input reads)
    const int* sr = src + (size_t)r * NE + (size_t)c * CHUNK;
    const int* dr = dst + (size_t)r * NE + (size_t)c * CHUNK;
    for (int i = tid; i < CHUNK; i += 512) {
        int d = dr[i];
        int s = sr[i];
        int b = d >> 8;
        int pos = atomicAdd(&lcnt[b], 1);
        if (pos < LCAP)
            lbuf[b][pos] = ((unsigned int)(d & 255) << 16) | (unsigned int)s;
    }
    __syncthreads();

    // exclusive scan of clamped counts (Hillis-Steele over 256)
    if (tid < 256)
        sa[tid] = (tid < NBUCK) ? min(lcnt[tid], LCAP) : 0;
    __syncthreads();
    int* cur = sa; int* nxt = sb;
    for (int st = 1; st < 256; st <<= 1) {
        if (tid < 256) {
            int v = cur[tid];
            if (tid >= st) v += cur[tid - st];
            nxt[tid] = v;
        }
        __syncthreads();
        int* t = cur; cur = nxt; nxt = t;
    }
    if (tid == 0) lofs[0] = 0;
    if (tid < NBUCK) lofs[tid + 1] = cur[tid];
    __syncthreads();

    // offsets out (coalesced)
    if (tid < NBUCK + 1) glofs[(size_t)blk * LSTRIDE + tid] = lofs[tid];

    // flush bucket runs to the block-private region: wave w -> buckets w, w+8, ...
    const int w = tid >> 6, l = tid & 63;
    unsigned int* gb = gbuck + (size_t)blk * BSTRIDE;
    for (int b = w; b < NBUCK; b += 8) {
        int cnt = min(lcnt[b], LCAP);            // cnt <= 56 < 64: one pass
        if (l < cnt) gb[lofs[b] + l] = lbuf[b][l];
    }
}

// ---------------------------------------------------------------------------
// Binning phase B: one block per (relation,bucket). Gather the 256 per-block
// runs (each ~16 entries = one 64B line), LDS-bin into 256-node slot lists,
// write slots + deg fully coalesced. No global atomics.
// ---------------------------------------------------------------------------
__global__ __launch_bounds__(512)
void bin_build_kernel(const unsigned int* __restrict__ gbuck,
                      const int* __restrict__ glofs,
                      unsigned short* __restrict__ slots,   // [NR*NN][SLOT]
                      int* __restrict__ deg)                // [NR*NN]
{
    __shared__ unsigned short lslot[256][SLOT];   // 32 KB
    __shared__ int lcnt[256];

    const int rb = blockIdx.x;                    // 0 .. NR*NBUCK-1
    const int r  = rb / NBUCK, b = rb - r * NBUCK;
    const int nbase = b * 256;
    int nb = NN - nbase; if (nb > 256) nb = 256;
    const int tid = threadIdx.x;

    for (int i = tid; i < 256; i += 512) lcnt[i] = 0;
    __syncthreads();

    // 2 threads per source block
    const int blk  = tid >> 1;
    const int half = tid & 1;
    const int gblk = r * P1B + blk;
    int o0 = glofs[(size_t)gblk * LSTRIDE + b];
    int o1 = glofs[(size_t)gblk * LSTRIDE + b + 1];
    const unsigned int* run = gbuck + (size_t)gblk * BSTRIDE + o0;
    int cnt = o1 - o0;
    for (int i = half; i < cnt; i += 2) {
        unsigned int e = run[i];
        int nl = e >> 16;                          // dst & 255
        int pos = atomicAdd(&lcnt[nl], 1);
        if (pos < SLOT) lslot[nl][pos] = (unsigned short)(e & 0xffffu);
    }
    __syncthreads();

    for (int j = tid; j < nb; j += 512) deg[r * NN + nbase + j] = lcnt[j];

    const unsigned int* ls32 = reinterpret_cast<const unsigned int*>(&lslot[0][0]);
    unsigned int* gs32 = reinterpret_cast<unsigned int*>(
        slots + ((size_t)r * NN + nbase) * SLOT);
    const int tot = nb * (SLOT / 2);
    for (int i = tid; i < tot; i += 512) gs32[i] = ls32[i];
}

// ---- f32 -> bf16 bulk convert (8 elems/thread) -----------------------------
__global__ void f32_to_bf16_kernel(const float* __restrict__ in,
                                   unsigned short* __restrict__ out, int n)
{
    int i = (blockIdx.x * 256 + threadIdx.x) * 8;
    if (i >= n) return;
    float4 a = *reinterpret_cast<const float4*>(in + i);
    float4 b = *reinterpret_cast<const float4*>(in + i + 4);
    uint4 o;
    o.x = pack2(a.x, a.y);
    o.y = pack2(a.z, a.w);
    o.z = pack2(b.x, b.y);
    o.w = pack2(b.z, b.w);
    *reinterpret_cast<uint4*>(out + i) = o;
}

// ---- weight transpose: W[r][k][n] f32 -> WT[r][n][k] bf16 ------------------
__global__ void wT_kernel(const float* __restrict__ in,
                          unsigned short* __restrict__ out,
                          int KD, int ND, int tot)
{
    int gid = blockIdx.x * 256 + threadIdx.x;
    if (gid >= tot) return;
    int k = gid % KD;
    int rn = gid / KD;
    int n = rn % ND;
    int r = rn / ND;
    out[gid] = f2b(in[((size_t)r * KD + k) * ND + n]);
}

// ---------------------------------------------------------------------------
// Mean-aggregation, all 3 relations, full 96 dims. 16 lanes per (rel,node);
// lane t gathers 12B (dwords 3t..3t+2) of each 192B source row (dwordx3).
// Slot indices fetched 8-at-a-time as uint4 (broadcast across the 16 lanes).
// ---------------------------------------------------------------------------
__global__ __launch_bounds__(256)
void agg_kernel(const unsigned int* __restrict__ Hb,        // [NN][48] dwords
                const unsigned short* __restrict__ slots,   // [NR*NN][SLOT]
                const int* __restrict__ deg,                // [NR*NN]
                unsigned int* __restrict__ aggb)            // [NR][NN][48]
{
    int gid = blockIdx.x * 256 + threadIdx.x;
    int grp = gid >> 4, t = gid & 15;
    if (grp >= NR * NN) return;
    const unsigned short* sl = slots + (size_t)grp * SLOT;
    int e = deg[grp];
    if (e > SLOT) e = SLOT;

    float a0 = 0.f, a1 = 0.f, a2 = 0.f, a3 = 0.f, a4 = 0.f, a5 = 0.f;
    int i = 0;
    for (; i + 8 <= e; i += 8) {
        uint4 iv = *reinterpret_cast<const uint4*>(sl + i);   // 8 u16 indices
        unsigned int idx[8] = { iv.x & 0xffffu, iv.x >> 16,
                                iv.y & 0xffffu, iv.y >> 16,
                                iv.z & 0xffffu, iv.z >> 16,
                                iv.w & 0xffffu, iv.w >> 16 };
        U3 v[8];
        #pragma unroll
        for (int q = 0; q < 8; ++q)
            v[q] = *reinterpret_cast<const U3*>(Hb + (size_t)idx[q] * 48 + 3 * t);
        #pragma unroll
        for (int q = 0; q < 8; ++q) {
            a0 += blo(v[q].x); a1 += bhi(v[q].x);
            a2 += blo(v[q].y); a3 += bhi(v[q].y);
            a4 += blo(v[q].z); a5 += bhi(v[q].z);
        }
    }
    for (; i < e; ++i) {
        unsigned int idx = sl[i];
        U3 v = *reinterpret_cast<const U3*>(Hb + (size_t)idx * 48 + 3 * t);
        a0 += blo(v.x); a1 += bhi(v.x);
        a2 += blo(v.y); a3 += bhi(v.y);
        a4 += blo(v.z); a5 += bhi(v.z);
    }
    float inv = 1.0f / (float)(e > 0 ? e : 1);
    unsigned int* o = aggb + (size_t)grp * 48 + 3 * t;   // grp = r*NN+n
    o[0] = pack2(a0 * inv, a1 * inv);
    o[1] = pack2(a2 * inv, a3 * inv);
    o[2] = pack2(a4 * inv, a5 * inv);
}

// ---------------------------------------------------------------------------
// MFMA layer: 4 waves/block, each wave owns 16 nodes and computes all NOUT
// cols for all 3 relations:  res = mean_r tanh(X@Ws_r + AGG_r@Wn_r + b_r).
// A-frags: lane l holds row (l&15), k = (l>>4)*8..+7 -> 16B contiguous loads
// from row-major bf16. B-frags from pre-transposed WT[n][k] (L2-hot).
// D-layout (m89-verified): col = lane&15, row = (lane>>4)*4 + j.
// Layer 1 writes o16 IN PLACE over Hb (each row is read only by its owner
// wave's A-frag loads, which precede its stores; clamped tail reads are
// discarded) -- saves a 9.6MB buffer.
// ---------------------------------------------------------------------------
template <int NOUT, bool OUT16>
__global__ __launch_bounds__(256)
void mfma_layer_kernel(const unsigned short* Hb,                // [NN][96] (may alias o16)
                       const unsigned short* __restrict__ aggb, // [NR][NN][96]
                       const unsigned short* __restrict__ Wts,  // [NR][NOUT][96] bf16 (Ws^T)
                       const unsigned short* __restrict__ Wtn,  // [NR][NOUT][96]
                       const float* __restrict__ bias,          // [NR][NOUT]
                       unsigned short* o16,                     // [NN][96] bf16
                       float* __restrict__ o32)                 // [NN][NOUT] f32
{
    const int w    = threadIdx.x >> 6;           // wave 0..3
    const int l    = threadIdx.x & 63;
    const int n0   = blockIdx.x * 64 + w * 16;   // wave's first node
    const int arow = l & 15, asel = l >> 4;
    int na = n0 + arow;
    if (na > NN - 1) na = NN - 1;                // clamp (stores guarded)

    bf16x8 ax[3], ag[NR][3];
    {
        const unsigned short* xr = Hb + (size_t)na * 96 + asel * 8;
        #pragma unroll
        for (int kb = 0; kb < 3; ++kb)
            ax[kb] = *reinterpret_cast<const bf16x8*>(xr + kb * 32);
        #pragma unroll
        for (int r = 0; r < NR; ++r) {
            const unsigned short* gr = aggb + ((size_t)r * NN + na) * 96 + asel * 8;
            #pragma unroll
            for (int kb = 0; kb < 3; ++kb)
                ag[r][kb] = *reinterpret_cast<const bf16x8*>(gr + kb * 32);
        }
    }

    constexpr int NC = NOUT / 16;
    #pragma unroll
    for (int c = 0; c < NC; ++c) {
        f32x4 acc[NR];
        #pragma unroll
        for (int r = 0; r < NR; ++r) acc[r] = (f32x4){0.f, 0.f, 0.f, 0.f};

        #pragma unroll
        for (int r = 0; r < NR; ++r) {
            const unsigned short* bs = Wts + ((size_t)r * NOUT + c * 16 + arow) * 96 + asel * 8;
            const unsigned short* bn = Wtn + ((size_t)r * NOUT + c * 16 + arow) * 96 + asel * 8;
            #pragma unroll
            for (int kb = 0; kb < 3; ++kb) {
                acc[r] = __builtin_amdgcn_mfma_f32_16x16x32_bf16(
                    ax[kb], *reinterpret_cast<const bf16x8*>(bs + kb * 32), acc[r], 0, 0, 0);
                acc[r] = __builtin_amdgcn_mfma_f32_16x16x32_bf16(
                    ag[r][kb], *reinterpret_cast<const bf16x8*>(bn + kb * 32), acc[r], 0, 0, 0);
            }
        }

        const int col = c * 16 + arow;
        const float b0 = bias[col];
        const float b1 = bias[NOUT + col];
        const float b2 = bias[2 * NOUT + col];
        #pragma unroll
        for (int j = 0; j < 4; ++j) {
            int node = n0 + asel * 4 + j;
            if (node < NN) {
                float v = (tanhf(acc[0][j] + b0) + tanhf(acc[1][j] + b1)
                         + tanhf(acc[2][j] + b2)) * (1.0f / 3.0f);
                if (OUT16) o16[(size_t)node * 96 + col] = f2b(v);
                else       o32[(size_t)node * DOUT + col] = v;
            }
        }
    }
}

// ---------------------------------------------------------------------------
extern "C" void kernel_launch(void* const* d_in, const int* in_sizes, int n_in,
                              void* d_out, int out_size, void* d_ws, size_t ws_size,
                              hipStream_t stream)
{
    const float* x   = (const float*)d_in[0];
    const int*   src = (const int*)d_in[1];
    const int*   dst = (const int*)d_in[2];
    const float* Ws1 = (const float*)d_in[3];
    const float* Wn1 = (const float*)d_in[4];
    const float* b1  = (const float*)d_in[5];
    const float* Ws2 = (const float*)d_in[6];
    const float* Wn2 = (const float*)d_in[7];
    const float* b2  = (const float*)d_in[8];
    float* out = (float*)d_out;

    // Workspace layout (256B-aligned), ~58.4 MB total (same as rounds 5/6).
    char* ws = (char*)d_ws;
    size_t o = 0;
    auto alloc = [&](size_t bytes) {
        size_t p = o;
        o += (bytes + 255) & ~(size_t)255;
        return p;
    };
    int* deg = (int*)(ws + alloc((size_t)NR * NN * 4));                          // 0.6 MB
    unsigned short* slots = (unsigned short*)(ws + alloc((size_t)NR * NN * SLOT * 2)); // 19.2 MB
    unsigned short* xb = (unsigned short*)(ws + alloc((size_t)NN * 96 * 2));     // 9.6 MB (x, then h1 in place)
    unsigned short* aggb = (unsigned short*)(ws + alloc((size_t)NR * NN * 96 * 2)); // 28.8 MB
    unsigned short* wt = (unsigned short*)(ws + alloc((size_t)(2 * NR * DIN * DH
                                                    + 2 * NR * DH * DOUT) * 2)); // 0.18 MB
    unsigned short* wt1s = wt;                         // [3][96][96]
    unsigned short* wt1n = wt1s + NR * DIN * DH;       // [3][96][96]
    unsigned short* wt2s = wt1n + NR * DIN * DH;       // [3][64][96]
    unsigned short* wt2n = wt2s + NR * DH * DOUT;      // [3][64][96]
    // Binning scratch (9.83 MB + 0.61 MB) aliases aggb: binning completes
    // before the first agg_kernel writes aggb (same stream, sequential).
    unsigned int* gbuck = (unsigned int*)aggb;                       // [768][3200] u32
    int* glofs = (int*)((char*)aggb + (size_t)NR * P1B * BSTRIDE * 4); // [768][200] i32

    // --- binning: two kernels, ZERO global atomics, no memsets ---
    bin_scatter_kernel<<<NR * P1B, 512, 0, stream>>>(src, dst, gbuck, glofs);
    bin_build_kernel<<<NR * NBUCK, 512, 0, stream>>>(gbuck, glofs, slots, deg);

    // --- dtype/layout prep ---
    f32_to_bf16_kernel<<<(NN * 96 / 8 + 255) / 256, 256, 0, stream>>>(x, xb, NN * 96);
    wT_kernel<<<(NR * DIN * DH + 255) / 256, 256, 0, stream>>>(Ws1, wt1s, DIN, DH, NR * DIN * DH);
    wT_kernel<<<(NR * DIN * DH + 255) / 256, 256, 0, stream>>>(Wn1, wt1n, DIN, DH, NR * DIN * DH);
    wT_kernel<<<(NR * DH * DOUT + 255) / 256, 256, 0, stream>>>(Ws2, wt2s, DH, DOUT, NR * DH * DOUT);
    wT_kernel<<<(NR * DH * DOUT + 255) / 256, 256, 0, stream>>>(Wn2, wt2n, DH, DOUT, NR * DH * DOUT);

    constexpr int AGG_GRID  = NR * NN * 16 / 256;      // 9375
    constexpr int GEMM_GRID = (NN + 63) / 64;          // 782

    // --- Layer 1: h1 (bf16, in place over xb) ---
    agg_kernel<<<AGG_GRID, 256, 0, stream>>>(
        (const unsigned int*)xb, slots, deg, (unsigned int*)aggb);
    mfma_layer_kernel<DH, true><<<GEMM_GRID, 256, 0, stream>>>(
        xb, aggb, wt1s, wt1n, b1, xb, (float*)nullptr);

    // --- Layer 2: out (f32) ---
    agg_kernel<<<AGG_GRID, 256, 0, stream>>>(
        (const unsigned int*)xb, slots, deg, (unsigned int*)aggb);
    mfma_layer_kernel<DOUT, false><<<GEMM_GRID, 256, 0, stream>>>(
        xb, aggb, wt2s, wt2n, b2, (unsigned short*)nullptr, out);
}

// Round 8
// 210.808 us; speedup vs baseline: 2.2746x; 1.1098x over previous
//
#include <hip/hip_runtime.h>
#include <hip/hip_bf16.h>

// Problem constants (fixed by reference)
constexpr int NN   = 50000;   // nodes
constexpr int NE   = 800000;  // edges per relation
constexpr int NR   = 3;       // relations
constexpr int DIN  = 96;
constexpr int DH   = 96;
constexpr int DOUT = 64;
constexpr int SLOT = 64;      // max in-degree slots (Poisson(16): P(>64) ~ 1e-22)
constexpr int ZROW = NN;      // reserved all-zero feature row (padding target)

// Binning parameters (zero global atomics; block-private runs + scan offsets)
constexpr int NBUCK   = 196;       // bucket = dst >> 8 (256 nodes per bucket)
constexpr int LCAP    = 56;        // per-(block,bucket) cap; Poisson(16) P(>56)~1e-11
constexpr int P1B     = 256;       // scatter blocks per relation
constexpr int CHUNK   = NE / P1B;  // 3125 edges per block (exact)
constexpr int BSTRIDE = 3200;      // gbuck ints per block
constexpr int LSTRIDE = 200;       // lofs ints per block (197 used)

// Fused prep kernel block ranges
constexpr int SCAT_BLKS = NR * P1B;                 // 768
constexpr int CONV_BLKS = (NN * 96 + 4095) / 4096;  // 1172 (512 thr x 8 f32)
constexpr int WT_ELEMS  = 2 * NR * DIN * DH + 2 * NR * DH * DOUT;  // 92160
constexpr int WT_BLKS   = (WT_ELEMS + 511) / 512;   // 180
constexpr int PREP_GRID = SCAT_BLKS + CONV_BLKS + WT_BLKS;

typedef __attribute__((ext_vector_type(8))) short bf16x8;  // MFMA A/B frag (4 VGPRs)
typedef __attribute__((ext_vector_type(4))) float f32x4;   // MFMA C/D frag

// ---- bf16 helpers (RNE) ----------------------------------------------------
__device__ __forceinline__ unsigned short f2b(float f) {
    unsigned int u = __float_as_uint(f);
    u += 0x7fffu + ((u >> 16) & 1u);       // round-to-nearest-even
    return (unsigned short)(u >> 16);
}
__device__ __forceinline__ float blo(unsigned int u) { return __uint_as_float(u << 16); }
__device__ __forceinline__ float bhi(unsigned int u) { return __uint_as_float(u & 0xffff0000u); }
__device__ __forceinline__ unsigned int pack2(float lo, float hi) {
    return (unsigned int)f2b(lo) | ((unsigned int)f2b(hi) << 16);
}

struct __align__(4) U3 { unsigned int x, y, z; };          // 12B row-slice gather

// ---------------------------------------------------------------------------
// Fused prep: [0,768) edge scatter into block-private bucket runs (no global
// atomics); [768,1940) x f32->bf16 (+ zero row ZROW); [1940,2120) weight
// transposes f32->bf16. All branches independent; scatter blocks dispatch
// first (they are the critical path for bin_build).
// ---------------------------------------------------------------------------
__global__ __launch_bounds__(512)
void prep_kernel(const int* __restrict__ src,
                 const int* __restrict__ dst,
                 unsigned int* __restrict__ gbuck,   // [NR*P1B][BSTRIDE]
                 int* __restrict__ glofs,            // [NR*P1B][LSTRIDE]
                 const float* __restrict__ x,
                 unsigned short* __restrict__ xb,    // [(NN+1)][96]
                 const float* __restrict__ Ws1, const float* __restrict__ Wn1,
                 const float* __restrict__ Ws2, const float* __restrict__ Wn2,
                 unsigned short* __restrict__ wt)    // packed transposed weights
{
    __shared__ unsigned int lbuf[NBUCK][LCAP];   // 43.9 KB (scatter branch only)
    __shared__ int lcnt[NBUCK];
    __shared__ int sa[256], sb[256];
    __shared__ int lofs[NBUCK + 1];

    const int bid = blockIdx.x;
    const int tid = threadIdx.x;

    if (bid < SCAT_BLKS) {
        // ---- edge scatter ----
        const int r = bid >> 8, c = bid & 255;
        for (int i = tid; i < NBUCK; i += 512) lcnt[i] = 0;
        __syncthreads();

        const int* sr = src + (size_t)r * NE + (size_t)c * CHUNK;
        const int* dr = dst + (size_t)r * NE + (size_t)c * CHUNK;
        for (int i = tid; i < CHUNK; i += 512) {
            int d = dr[i];
            int s = sr[i];
            int b = d >> 8;
            int pos = atomicAdd(&lcnt[b], 1);
            if (pos < LCAP)
                lbuf[b][pos] = ((unsigned int)(d & 255) << 16) | (unsigned int)s;
        }
        __syncthreads();

        if (tid < 256)
            sa[tid] = (tid < NBUCK) ? min(lcnt[tid], LCAP) : 0;
        __syncthreads();
        int* cur = sa; int* nxt = sb;
        for (int st = 1; st < 256; st <<= 1) {
            if (tid < 256) {
                int v = cur[tid];
                if (tid >= st) v += cur[tid - st];
                nxt[tid] = v;
            }
            __syncthreads();
            int* t2 = cur; cur = nxt; nxt = t2;
        }
        if (tid == 0) lofs[0] = 0;
        if (tid < NBUCK) lofs[tid + 1] = cur[tid];
        __syncthreads();

        if (tid < NBUCK + 1) glofs[(size_t)bid * LSTRIDE + tid] = lofs[tid];

        const int w = tid >> 6, l = tid & 63;
        unsigned int* gb = gbuck + (size_t)bid * BSTRIDE;
        for (int b = w; b < NBUCK; b += 8) {
            int cnt = min(lcnt[b], LCAP);
            if (l < cnt) gb[lofs[b] + l] = lbuf[b][l];
        }
    } else if (bid < SCAT_BLKS + CONV_BLKS) {
        // ---- x -> bf16 + zero row ----
        const int rb = bid - SCAT_BLKS;
        if (rb == 0 && tid < 48) {
            unsigned int* z = reinterpret_cast<unsigned int*>(xb + (size_t)ZROW * 96);
            z[tid] = 0u;
        }
        int i = (rb * 512 + tid) * 8;
        if (i < NN * 96) {
            float4 a = *reinterpret_cast<const float4*>(x + i);
            float4 b = *reinterpret_cast<const float4*>(x + i + 4);
            uint4 o;
            o.x = pack2(a.x, a.y);
            o.y = pack2(a.z, a.w);
            o.z = pack2(b.x, b.y);
            o.w = pack2(b.z, b.w);
            *reinterpret_cast<uint4*>(xb + i) = o;
        }
    } else {
        // ---- weight transposes: W[r][k][n] f32 -> WT[r][n][k] bf16 ----
        int g = (bid - SCAT_BLKS - CONV_BLKS) * 512 + tid;
        if (g < WT_ELEMS) {
            constexpr int SZ1 = NR * DIN * DH;     // 27648
            constexpr int SZ2 = NR * DH * DOUT;    // 18432
            const float* in;
            int idx, KD, ND;
            if (g < SZ1)                { in = Ws1; idx = g;                KD = DIN; ND = DH; }
            else if (g < 2 * SZ1)       { in = Wn1; idx = g - SZ1;          KD = DIN; ND = DH; }
            else if (g < 2 * SZ1 + SZ2) { in = Ws2; idx = g - 2 * SZ1;      KD = DH;  ND = DOUT; }
            else                        { in = Wn2; idx = g - 2 * SZ1 - SZ2; KD = DH; ND = DOUT; }
            int k = idx % KD;
            int rn = idx / KD;
            int n = rn % ND;
            int r = rn / ND;
            wt[g] = f2b(in[((size_t)r * KD + k) * ND + n]);
        }
    }
}

// ---------------------------------------------------------------------------
// Binning phase B: one block per (relation,bucket). Gather the 256 per-block
// runs, LDS-bin into 256-node slot lists (unused entries pre-filled with
// ZROW so agg can gather unconditionally), write slots + deg coalesced.
// ---------------------------------------------------------------------------
__global__ __launch_bounds__(512)
void bin_build_kernel(const unsigned int* __restrict__ gbuck,
                      const int* __restrict__ glofs,
                      unsigned short* __restrict__ slots,   // [NR*NN][SLOT]
                      int* __restrict__ deg)                // [NR*NN]
{
    __shared__ unsigned short lslot[256][SLOT];   // 32 KB
    __shared__ int lcnt[256];

    const int rb = blockIdx.x;                    // 0 .. NR*NBUCK-1
    const int r  = rb / NBUCK, b = rb - r * NBUCK;
    const int nbase = b * 256;
    int nb = NN - nbase; if (nb > 256) nb = 256;
    const int tid = threadIdx.x;

    // pre-fill slots with ZROW (0xC350) so padded gathers read the zero row
    unsigned int* ls32i = reinterpret_cast<unsigned int*>(&lslot[0][0]);
    for (int i = tid; i < 256 * SLOT / 2; i += 512) ls32i[i] = 0xC350C350u;
    for (int i = tid; i < 256; i += 512) lcnt[i] = 0;
    __syncthreads();

    const int blk  = tid >> 1;
    const int half = tid & 1;
    const int gblk = r * P1B + blk;
    int o0 = glofs[(size_t)gblk * LSTRIDE + b];
    int o1 = glofs[(size_t)gblk * LSTRIDE + b + 1];
    const unsigned int* run = gbuck + (size_t)gblk * BSTRIDE + o0;
    int cnt = o1 - o0;
    for (int i = half; i < cnt; i += 2) {
        unsigned int e = run[i];
        int nl = e >> 16;                          // dst & 255
        int pos = atomicAdd(&lcnt[nl], 1);
        if (pos < SLOT) lslot[nl][pos] = (unsigned short)(e & 0xffffu);
    }
    __syncthreads();

    for (int j = tid; j < nb; j += 512) deg[r * NN + nbase + j] = lcnt[j];

    const unsigned int* ls32 = reinterpret_cast<const unsigned int*>(&lslot[0][0]);
    unsigned int* gs32 = reinterpret_cast<unsigned int*>(
        slots + ((size_t)r * NN + nbase) * SLOT);
    const int tot = nb * (SLOT / 2);
    for (int i = tid; i < tot; i += 512) gs32[i] = ls32[i];
}

// ---------------------------------------------------------------------------
// Mean-aggregation, all 3 relations, full 96 dims. 16 lanes per (rel,node);
// lane t gathers 12B (dwords 3t..3t+2) of each 192B row. Branch-free batches
// of 8 edges: padding indices point at the all-zero ZROW (L1-hot, harmless).
// All 32 first-edge indices preloaded eagerly -> up to 32 gathers in flight.
// ---------------------------------------------------------------------------
__global__ __launch_bounds__(256)
void agg_kernel(const unsigned int* __restrict__ Hb,        // [(NN+1)][48] dwords
                const unsigned short* __restrict__ slots,   // [NR*NN][SLOT]
                const int* __restrict__ deg,                // [NR*NN]
                unsigned int* __restrict__ aggb)            // [NR][NN][48]
{
    int gid = blockIdx.x * 256 + threadIdx.x;
    int grp = gid >> 4, t = gid & 15;
    if (grp >= NR * NN) return;
    const uint4* sl4 = reinterpret_cast<const uint4*>(slots + (size_t)grp * SLOT);
    int e = deg[grp];
    if (e > SLOT) e = SLOT;

    // eager index preload: first 32 edges (64B); padded entries are ZROW
    uint4 iv0 = sl4[0], iv1 = sl4[1], iv2 = sl4[2], iv3 = sl4[3];

    float a0 = 0.f, a1 = 0.f, a2 = 0.f, a3 = 0.f, a4 = 0.f, a5 = 0.f;

#define DO8(V)                                                                 \
    {                                                                          \
        unsigned int i0 = (V).x & 0xffffu, i1 = (V).x >> 16;                   \
        unsigned int i2 = (V).y & 0xffffu, i3 = (V).y >> 16;                   \
        unsigned int i4 = (V).z & 0xffffu, i5 = (V).z >> 16;                   \
        unsigned int i6 = (V).w & 0xffffu, i7 = (V).w >> 16;                   \
        U3 g0 = *reinterpret_cast<const U3*>(Hb + (size_t)i0 * 48 + 3 * t);    \
        U3 g1 = *reinterpret_cast<const U3*>(Hb + (size_t)i1 * 48 + 3 * t);    \
        U3 g2 = *reinterpret_cast<const U3*>(Hb + (size_t)i2 * 48 + 3 * t);    \
        U3 g3 = *reinterpret_cast<const U3*>(Hb + (size_t)i3 * 48 + 3 * t);    \
        U3 g4 = *reinterpret_cast<const U3*>(Hb + (size_t)i4 * 48 + 3 * t);    \
        U3 g5 = *reinterpret_cast<const U3*>(Hb + (size_t)i5 * 48 + 3 * t);    \
        U3 g6 = *reinterpret_cast<const U3*>(Hb + (size_t)i6 * 48 + 3 * t);    \
        U3 g7 = *reinterpret_cast<const U3*>(Hb + (size_t)i7 * 48 + 3 * t);    \
        a0 += blo(g0.x) + blo(g1.x) + blo(g2.x) + blo(g3.x)                    \
            + blo(g4.x) + blo(g5.x) + blo(g6.x) + blo(g7.x);                   \
        a1 += bhi(g0.x) + bhi(g1.x) + bhi(g2.x) + bhi(g3.x)                    \
            + bhi(g4.x) + bhi(g5.x) + bhi(g6.x) + bhi(g7.x);                   \
        a2 += blo(g0.y) + blo(g1.y) + blo(g2.y) + blo(g3.y)                    \
            + blo(g4.y) + blo(g5.y) + blo(g6.y) + blo(g7.y);                   \
        a3 += bhi(g0.y) + bhi(g1.y) + bhi(g2.y) + bhi(g3.y)                    \
            + bhi(g4.y) + bhi(g5.y) + bhi(g6.y) + bhi(g7.y);                   \
        a4 += blo(g0.z) + blo(g1.z) + blo(g2.z) + blo(g3.z)                    \
            + blo(g4.z) + blo(g5.z) + blo(g6.z) + blo(g7.z);                   \
        a5 += bhi(g0.z) + bhi(g1.z) + bhi(g2.z) + bhi(g3.z)                    \
            + bhi(g4.z) + bhi(g5.z) + bhi(g6.z) + bhi(g7.z);                   \
    }

    int nb8 = (e + 7) >> 3;                       // 8-edge batches
    if (nb8 > 0) DO8(iv0);
    if (nb8 > 1) DO8(iv1);
    if (nb8 > 2) DO8(iv2);
    if (nb8 > 3) DO8(iv3);
    for (int i = 32; i < e; i += 8) {             // P(e>32) ~ 1e-4
        uint4 v = sl4[i >> 3];
        DO8(v);
    }
#undef DO8

    float inv = 1.0f / (float)(e > 0 ? e : 1);
    unsigned int* o = aggb + (size_t)grp * 48 + 3 * t;   // grp = r*NN+n
    o[0] = pack2(a0 * inv, a1 * inv);
    o[1] = pack2(a2 * inv, a3 * inv);
    o[2] = pack2(a4 * inv, a5 * inv);
}

// ---------------------------------------------------------------------------
// MFMA layer: 4 waves/block, each wave owns 16 nodes and computes all NOUT
// cols for all 3 relations:  res = mean_r tanh(X@Ws_r + AGG_r@Wn_r + b_r).
// A-frags: lane l holds row (l&15), k = (l>>4)*8..+7 -> 16B contiguous loads
// from row-major bf16. B-frags from pre-transposed WT[n][k] (L2-hot).
// D-layout (m89-verified): col = lane&15, row = (lane>>4)*4 + j.
// Layer 1 writes o16 IN PLACE over Hb (each row is read only by its owner
// wave's A-frag loads, which precede its stores; clamped tail reads are
// discarded). Row ZROW is never written -> stays zero for layer 2.
// ---------------------------------------------------------------------------
template <int NOUT, bool OUT16>
__global__ __launch_bounds__(256)
void mfma_layer_kernel(const unsigned short* Hb,                // [(NN+1)][96] (may alias o16)
                       const unsigned short* __restrict__ aggb, // [NR][NN][96]
                       const unsigned short* __restrict__ Wts,  // [NR][NOUT][96] bf16 (Ws^T)
                       const unsigned short* __restrict__ Wtn,  // [NR][NOUT][96]
                       const float* __restrict__ bias,          // [NR][NOUT]
                       unsigned short* o16,                     // [(NN+1)][96] bf16
                       float* __restrict__ o32)                 // [NN][NOUT] f32
{
    const int w    = threadIdx.x >> 6;           // wave 0..3
    const int l    = threadIdx.x & 63;
    const int n0   = blockIdx.x * 64 + w * 16;   // wave's first node
    const int arow = l & 15, asel = l >> 4;
    int na = n0 + arow;
    if (na > NN - 1) na = NN - 1;                // clamp (stores guarded)

    bf16x8 ax[3], ag[NR][3];
    {
        const unsigned short* xr = Hb + (size_t)na * 96 + asel * 8;
        #pragma unroll
        for (int kb = 0; kb < 3; ++kb)
            ax[kb] = *reinterpret_cast<const bf16x8*>(xr + kb * 32);
        #pragma unroll
        for (int r = 0; r < NR; ++r) {
            const unsigned short* gr = aggb + ((size_t)r * NN + na) * 96 + asel * 8;
            #pragma unroll
            for (int kb = 0; kb < 3; ++kb)
                ag[r][kb] = *reinterpret_cast<const bf16x8*>(gr + kb * 32);
        }
    }

    constexpr int NC = NOUT / 16;
    #pragma unroll
    for (int c = 0; c < NC; ++c) {
        f32x4 acc[NR];
        #pragma unroll
        for (int r = 0; r < NR; ++r) acc[r] = (f32x4){0.f, 0.f, 0.f, 0.f};

        #pragma unroll
        for (int r = 0; r < NR; ++r) {
            const unsigned short* bs = Wts + ((size_t)r * NOUT + c * 16 + arow) * 96 + asel * 8;
            const unsigned short* bn = Wtn + ((size_t)r * NOUT + c * 16 + arow) * 96 + asel * 8;
            #pragma unroll
            for (int kb = 0; kb < 3; ++kb) {
                acc[r] = __builtin_amdgcn_mfma_f32_16x16x32_bf16(
                    ax[kb], *reinterpret_cast<const bf16x8*>(bs + kb * 32), acc[r], 0, 0, 0);
                acc[r] = __builtin_amdgcn_mfma_f32_16x16x32_bf16(
                    ag[r][kb], *reinterpret_cast<const bf16x8*>(bn + kb * 32), acc[r], 0, 0, 0);
            }
        }

        const int col = c * 16 + arow;
        const float b0 = bias[col];
        const float b1 = bias[NOUT + col];
        const float b2 = bias[2 * NOUT + col];
        #pragma unroll
        for (int j = 0; j < 4; ++j) {
            int node = n0 + asel * 4 + j;
            if (node < NN) {
                float v = (tanhf(acc[0][j] + b0) + tanhf(acc[1][j] + b1)
                         + tanhf(acc[2][j] + b2)) * (1.0f / 3.0f);
                if (OUT16) o16[(size_t)node * 96 + col] = f2b(v);
                else       o32[(size_t)node * DOUT + col] = v;
            }
        }
    }
}

// ---------------------------------------------------------------------------
extern "C" void kernel_launch(void* const* d_in, const int* in_sizes, int n_in,
                              void* d_out, int out_size, void* d_ws, size_t ws_size,
                              hipStream_t stream)
{
    const float* x   = (const float*)d_in[0];
    const int*   src = (const int*)d_in[1];
    const int*   dst = (const int*)d_in[2];
    const float* Ws1 = (const float*)d_in[3];
    const float* Wn1 = (const float*)d_in[4];
    const float* b1  = (const float*)d_in[5];
    const float* Ws2 = (const float*)d_in[6];
    const float* Wn2 = (const float*)d_in[7];
    const float* b2  = (const float*)d_in[8];
    float* out = (float*)d_out;

    // Workspace layout (256B-aligned), ~58.4 MB total.
    char* ws = (char*)d_ws;
    size_t o = 0;
    auto alloc = [&](size_t bytes) {
        size_t p = o;
        o += (bytes + 255) & ~(size_t)255;
        return p;
    };
    int* deg = (int*)(ws + alloc((size_t)NR * NN * 4));                          // 0.6 MB
    unsigned short* slots = (unsigned short*)(ws + alloc((size_t)NR * NN * SLOT * 2)); // 19.2 MB
    unsigned short* xb = (unsigned short*)(ws + alloc((size_t)(NN + 1) * 96 * 2)); // 9.6 MB (x/h1 + zero row)
    unsigned short* aggb = (unsigned short*)(ws + alloc((size_t)NR * NN * 96 * 2)); // 28.8 MB
    unsigned short* wt = (unsigned short*)(ws + alloc((size_t)WT_ELEMS * 2));    // 0.18 MB
    unsigned short* wt1s = wt;                         // [3][96][96]
    unsigned short* wt1n = wt1s + NR * DIN * DH;       // [3][96][96]
    unsigned short* wt2s = wt1n + NR * DIN * DH;       // [3][64][96]
    unsigned short* wt2n = wt2s + NR * DH * DOUT;      // [3][64][96]
    // Binning scratch aliases aggb (binning completes before agg writes aggb)
    unsigned int* gbuck = (unsigned int*)aggb;                         // [768][3200] u32
    int* glofs = (int*)((char*)aggb + (size_t)NR * P1B * BSTRIDE * 4); // [768][200] i32

    // --- fused prep: edge scatter + x->bf16 (+zero row) + weight transposes ---
    prep_kernel<<<PREP_GRID, 512, 0, stream>>>(
        src, dst, gbuck, glofs, x, xb, Ws1, Wn1, Ws2, Wn2, wt);

    // --- binning phase B (slot lists, ZROW-padded) ---
    bin_build_kernel<<<NR * NBUCK, 512, 0, stream>>>(gbuck, glofs, slots, deg);

    constexpr int AGG_GRID  = NR * NN * 16 / 256;      // 9375
    constexpr int GEMM_GRID = (NN + 63) / 64;          // 782

    // --- Layer 1: h1 (bf16, in place over xb) ---
    agg_kernel<<<AGG_GRID, 256, 0, stream>>>(
        (const unsigned int*)xb, slots, deg, (unsigned int*)aggb);
    mfma_layer_kernel<DH, true><<<GEMM_GRID, 256, 0, stream>>>(
        xb, aggb, wt1s, wt1n, b1, xb, (float*)nullptr);

    // --- Layer 2: out (f32) ---
    agg_kernel<<<AGG_GRID, 256, 0, stream>>>(
        (const unsigned int*)xb, slots, deg, (unsigned int*)aggb);
    mfma_layer_kernel<DOUT, false><<<GEMM_GRID, 256, 0, stream>>>(
        xb, aggb, wt2s, wt2n, b2, (unsigned short*)nullptr, out);
}